// Round 16
// baseline (555.855 us; speedup 1.0000x reference)
//
#include <hip/hip_runtime.h>
#include <math.h>

typedef unsigned short u16;
typedef short short8 __attribute__((ext_vector_type(8)));
typedef float f32x4 __attribute__((ext_vector_type(4)));

#define TT 4
#define BB 4096
#define DIM 512
#define HDIM 1024
#define BD (BB*DIM)      // 2097152
#define D2 (DIM*DIM)     // 262144
#define NEXP 20

#define GLOAD16(gp, lp) __builtin_amdgcn_global_load_lds( \
    (__attribute__((address_space(1))) void*)(void*)(gp), \
    (__attribute__((address_space(3))) void*)(void*)(lp), 16, 0, 0)

__device__ __forceinline__ u16 f2b(float f) {
  union { float f; unsigned u; } x; x.f = f;
  unsigned r = x.u + 0x7FFFu + ((x.u >> 16) & 1u);
  return (u16)(r >> 16);
}
__device__ __forceinline__ float b2f(u16 v) {
  union { unsigned u; float f; } x; x.u = ((unsigned)v) << 16; return x.f;
}

__device__ __forceinline__ float wsum(float v) {
#pragma unroll
  for (int o = 32; o > 0; o >>= 1) v += __shfl_xor(v, o);
  return v;
}

// fast exact-enough GELU
__device__ __forceinline__ float fgelu(float v) {
  float u = 1.5957691216057308f * v * (1.0f + 0.044715f * v * v);
  return v / (1.0f + __expf(-u));
}

// ------ prep: one wave per row b: mean, bf16 casts, score-bias sbias --------
__global__ __launch_bounds__(256) void k_prep(const float* __restrict__ ti,
                                              const float* __restrict__ qwkb,
                                              const float* __restrict__ kbqb,
                                              u16* __restrict__ tib,
                                              u16* __restrict__ xsb,
                                              float* __restrict__ sbias) {
  int gw = (blockIdx.x * 256 + threadIdx.x) >> 6;   // row b
  int lane = threadIdx.x & 63;
  int d0 = lane * 8;
  float x[4][8];
#pragma unroll
  for (int t = 0; t < 4; t++) {
    const float* p = ti + ((size_t)t * BB + gw) * DIM + d0;
    *(float4*)&x[t][0] = *(const float4*)p;
    *(float4*)&x[t][4] = *(const float4*)(p + 4);
  }
  float m[8];
#pragma unroll
  for (int j = 0; j < 8; j++)
    m[j] = (x[0][j] + x[1][j] + x[2][j] + x[3][j]) * 0.25f;
#pragma unroll
  for (int t = 0; t < 4; t++) {
    ushort4 c0 = { f2b(x[t][0]), f2b(x[t][1]), f2b(x[t][2]), f2b(x[t][3]) };
    ushort4 c1 = { f2b(x[t][4]), f2b(x[t][5]), f2b(x[t][6]), f2b(x[t][7]) };
    u16* q = tib + ((size_t)t * BB + gw) * DIM + d0;
    *(ushort4*)q = c0; *(ushort4*)(q + 4) = c1;
  }
  {
    ushort4 c0 = { f2b(m[0]), f2b(m[1]), f2b(m[2]), f2b(m[3]) };
    ushort4 c1 = { f2b(m[4]), f2b(m[5]), f2b(m[6]), f2b(m[7]) };
    u16* q = xsb + (size_t)gw * DIM + d0;
    *(ushort4*)q = c0; *(ushort4*)(q + 4) = c1;
  }
#pragma unroll
  for (int t = 0; t < 4; t++) {
    const float* wp = qwkb + (size_t)t * DIM + d0;
    float4 w0 = *(const float4*)wp, w1 = *(const float4*)(wp + 4);
    float s = x[t][0]*w0.x + x[t][1]*w0.y + x[t][2]*w0.z + x[t][3]*w0.w
            + x[t][4]*w1.x + x[t][5]*w1.y + x[t][6]*w1.z + x[t][7]*w1.w;
    s = wsum(s);
    if (lane == 0) sbias[(size_t)t * BB + gw] = s + kbqb[t];
  }
}

// ------------- batched transpose+cast: (G,R,C) f32 -> (G,C,R) bf16 -----------
__global__ __launch_bounds__(256) void k_tcast(const float* __restrict__ in,
                                               u16* __restrict__ out,
                                               int R, int C) {
  __shared__ float tile[32][33];
  size_t gb = (size_t)blockIdx.z * R * C;
  in += gb; out += gb;
  int c0 = blockIdx.x * 32, r0 = blockIdx.y * 32;
  int tx = threadIdx.x & 31, ty = threadIdx.x >> 5;
#pragma unroll
  for (int j = 0; j < 4; j++)
    tile[ty + j * 8][tx] = in[(size_t)(r0 + ty + j * 8) * C + c0 + tx];
  __syncthreads();
#pragma unroll
  for (int j = 0; j < 4; j++)
    out[(size_t)(c0 + ty + j * 8) * R + r0 + tx] = f2b(tile[tx][ty + j * 8]);
}

// ---------------- plain cast f32 -> bf16 -------------------------------------
__global__ __launch_bounds__(256) void k_cast(const float* __restrict__ in,
                                              u16* __restrict__ out) {
  size_t i = ((size_t)blockIdx.x * 256 + threadIdx.x) * 4;
  float4 v = *(const float4*)(in + i);
  ushort4 b = { f2b(v.x), f2b(v.y), f2b(v.z), f2b(v.w) };
  *(ushort4*)(out + i) = b;
}

// --------------- small bias-vector precomputes -------------------------------
__global__ __launch_bounds__(256) void k_biasvec(const float* __restrict__ qw,
                                                 const float* __restrict__ kb,
                                                 const float* __restrict__ kw,
                                                 const float* __restrict__ qb,
                                                 float* __restrict__ qwkb,
                                                 float* __restrict__ kwqb,
                                                 float* __restrict__ kbqb) {
  int gw = (blockIdx.x * 256 + threadIdx.x) >> 6;
  int lane = threadIdx.x & 63;
  if (gw < 2048) {
    int t = gw >> 9, c = gw & 511;
    const float* row = qw + ((size_t)t * DIM + c) * DIM;
    const float* v = kb + (size_t)t * DIM;
    float s = 0;
#pragma unroll
    for (int j = 0; j < 8; j++) s += row[lane * 8 + j] * v[lane * 8 + j];
    s = wsum(s);
    if (lane == 0) qwkb[(size_t)t * DIM + c] = s;
  } else if (gw < 4096) {
    int t = (gw - 2048) >> 9, d = gw & 511;
    const float* row = kw + ((size_t)t * DIM + d) * DIM;
    const float* v = qb + (size_t)t * DIM;
    float s = 0;
#pragma unroll
    for (int j = 0; j < 8; j++) s += row[lane * 8 + j] * v[lane * 8 + j];
    s = wsum(s);
    if (lane == 0) kwqb[(size_t)t * DIM + d] = s;
  } else if (gw < 4100) {
    int t = gw - 4096;
    const float* a = kb + (size_t)t * DIM;
    const float* c = qb + (size_t)t * DIM;
    float s = 0;
#pragma unroll
    for (int j = 0; j < 8; j++) s += a[lane * 8 + j] * c[lane * 8 + j];
    s = wsum(s);
    if (lane == 0) kbqb[t] = s;
  }
}

// ---- 256x256 bf16 MFMA GEMM, 512 thr, BK=32, triple-ring counted vmcnt ------
// 128 FLOP/byte staged. LDS 96 KB (3 x 2 x 16 KB) -> 1 block/CU, 8 waves;
// the ring (tile k+2 always in flight, never drains) supplies latency hiding.
// 4 loads/thread/tile (2 A-chunks + 2 B-chunks) -> vmcnt(4) counted waits.
template <bool SWAPPED>
__device__ __forceinline__ void gemm256r(const u16* __restrict__ Ag, int lda,
                                         const u16* __restrict__ Bg, int ldb,
                                         int K, f32x4 acc[8][4]) {
  __shared__ __align__(16) u16 lA[3][8192];   // 3 x (256 x 32)
  __shared__ __align__(16) u16 lB[3][8192];
  const int tid = threadIdx.x;                // 0..511
  const int lane = tid & 63;
  const int wave = tid >> 6;
  const int wm = wave >> 2, wn = wave & 3;    // 2 x 4 wave grid
  const int rl = lane & 15;
  const int hs = ((lane >> 4) ^ ((rl >> 1) & 3)) * 8;   // swizzled read chunk
  // staging: 2 chunks per matrix per thread; pre-swizzled global source
  const u16* aP[2]; const u16* bP[2];
  int dst[2];
#pragma unroll
  for (int i = 0; i < 2; i++) {
    int c16 = tid + 512 * i;                  // chunk id 0..1023
    int row = c16 >> 2;                       // 0..255
    int gch = (c16 & 3) ^ ((row >> 1) & 3);   // involution with read side
    aP[i] = Ag + (size_t)row * lda + gch * 8;
    bP[i] = Bg + (size_t)row * ldb + gch * 8;
    dst[i] = c16 * 8;
  }
  const int nst = K >> 5;
  // prologue: stage tiles 0 and 1
#pragma unroll
  for (int i = 0; i < 2; i++) { GLOAD16(aP[i], &lA[0][dst[i]]); GLOAD16(bP[i], &lB[0][dst[i]]); }
#pragma unroll
  for (int i = 0; i < 2; i++) { GLOAD16(aP[i] + 32, &lA[1][dst[i]]); GLOAD16(bP[i] + 32, &lB[1][dst[i]]); }
  asm volatile("s_waitcnt vmcnt(4)" ::: "memory");  // tile0 landed
  __builtin_amdgcn_s_barrier();
  __builtin_amdgcn_sched_barrier(0);
  for (int k = 0; k < nst; ++k) {
    const int cur = k % 3;
    if (k + 2 < nst) {                   // issue tile k+2 into ring slot
      const int off = (k + 2) * 32;
      const int nb = (k + 2) % 3;
#pragma unroll
      for (int i = 0; i < 2; i++) {
        GLOAD16(aP[i] + off, &lA[nb][dst[i]]);
        GLOAD16(bP[i] + off, &lB[nb][dst[i]]);
      }
    }
    short8 bf[4];
#pragma unroll
    for (int nf = 0; nf < 4; nf++)
      bf[nf] = *(const short8*)&lB[cur][(wn * 64 + nf * 16 + rl) * 32 + hs];
    __builtin_amdgcn_s_setprio(1);
#pragma unroll
    for (int mf = 0; mf < 8; mf++) {
      short8 af = *(const short8*)&lA[cur][(wm * 128 + mf * 16 + rl) * 32 + hs];
      if (SWAPPED) {
#pragma unroll
        for (int nf = 0; nf < 4; nf++)
          acc[mf][nf] = __builtin_amdgcn_mfma_f32_16x16x32_bf16(bf[nf], af,
                                                                acc[mf][nf], 0, 0, 0);
      } else {
#pragma unroll
        for (int nf = 0; nf < 4; nf++)
          acc[mf][nf] = __builtin_amdgcn_mfma_f32_16x16x32_bf16(af, bf[nf],
                                                                acc[mf][nf], 0, 0, 0);
      }
    }
    __builtin_amdgcn_s_setprio(0);
    // counted wait: tile k+1 landed; tile k+2 (4 loads) stays in flight
    if (k + 2 < nst) asm volatile("s_waitcnt vmcnt(4)" ::: "memory");
    else             asm volatile("s_waitcnt vmcnt(0)" ::: "memory");
    __builtin_amdgcn_s_barrier();
    __builtin_amdgcn_sched_barrier(0);
  }
}

// ---------------- expert up-GEMM: h = gelu(x@W1 + b1), bf16 out --------------
// 256x256 tile, non-swapped epilogue: row=(lane>>4)*4+r, col=lane&15.
__global__ __launch_bounds__(512, 2) void k_gemm_up(const u16* __restrict__ xsb,
                                                 const u16* __restrict__ tib,
                                                 const u16* __restrict__ w1t,
                                                 const float* __restrict__ sb1,
                                                 const float* __restrict__ tb1,
                                                 u16* __restrict__ hbuf,
                                                 int row0, int SR) {
  int ge = blockIdx.z;
  const u16* A;
  const float* bias;
  if (ge < 4) { A = xsb; bias = sb1 + (size_t)ge * HDIM; }
  else {
    int te = ge - 4;
    A = tib + (size_t)(te >> 2) * BD;
    bias = tb1 + (size_t)te * HDIM;
  }
  A += (size_t)row0 * DIM;
  const u16* W = w1t + (size_t)ge * ((size_t)HDIM * DIM);
  int m0 = blockIdx.y * 256, n0 = blockIdx.x * 256;
  f32x4 acc[8][4] = {};
  gemm256r<false>(A + (size_t)m0 * DIM, DIM, W + (size_t)n0 * DIM, DIM, DIM, acc);
  u16* out = hbuf + (size_t)ge * ((size_t)SR * HDIM);
  const int lane = threadIdx.x & 63, wave = threadIdx.x >> 6;
  const int rbase = m0 + (wave >> 2) * 128 + (lane >> 4) * 4;
  const int cbase = n0 + (wave & 3) * 64 + (lane & 15);
#pragma unroll
  for (int mi = 0; mi < 8; mi++)
#pragma unroll
    for (int ni = 0; ni < 4; ni++)
#pragma unroll
      for (int r = 0; r < 4; r++) {
        int row = rbase + mi * 16 + r;
        int col = cbase + ni * 16;
        float v = acc[mi][ni][r] + bias[col];
        out[(size_t)row * HDIM + col] = f2b(fgelu(v));
      }
}

// ---- down-GEMM: preLN bf16 = h@W2 + b2 + residual -> stk16[20][B][D] --------
// 256x256 tile, swapped epilogue: lane owns (row=rl, 4 cols) -> ushort4.
__global__ __launch_bounds__(512, 2) void k_gemm_down(const u16* __restrict__ hbuf,
                                                   const u16* __restrict__ w2t,
                                                   const float* __restrict__ sb2,
                                                   const float* __restrict__ tb2,
                                                   const u16* __restrict__ xsb,
                                                   const u16* __restrict__ tib,
                                                   u16* __restrict__ stk16,
                                                   int row0, int SR) {
  int ge = blockIdx.z;
  int m0 = blockIdx.y * 256, n0 = blockIdx.x * 256;
  const u16* Ag = hbuf + (size_t)ge * ((size_t)SR * HDIM) + (size_t)m0 * HDIM;
  const u16* Bg = w2t + (size_t)ge * ((size_t)DIM * HDIM) + (size_t)n0 * HDIM;
  f32x4 acc[8][4] = {};
  gemm256r<true>(Ag, HDIM, Bg, HDIM, HDIM, acc);
  const float* bias; const u16* resb;
  int te = ge - 4;
  if (ge < 4) { bias = sb2 + (size_t)ge * DIM; resb = xsb; }
  else { bias = tb2 + (size_t)te * DIM; resb = tib + (size_t)(te >> 2) * BD; }
  const int lane = threadIdx.x & 63, wave = threadIdx.x >> 6;
  const int rl = lane & 15, c4 = (lane >> 4) * 4;
  const int wm = wave >> 2, wn = wave & 3;
  u16* outb = stk16 + (size_t)ge * BD;
#pragma unroll
  for (int mf = 0; mf < 8; mf++) {
    int grow = row0 + m0 + wm * 128 + mf * 16 + rl;
#pragma unroll
    for (int nf = 0; nf < 4; nf++) {
      int col0 = n0 + wn * 64 + nf * 16 + c4;
      float4 bb = *(const float4*)(bias + col0);
      ushort4 rr = *(const ushort4*)(resb + (size_t)grow * DIM + col0);
      ushort4 y;
      y.x = f2b(acc[mf][nf][0] + bb.x + b2f(rr.x));
      y.y = f2b(acc[mf][nf][1] + bb.y + b2f(rr.y));
      y.z = f2b(acc[mf][nf][2] + bb.z + b2f(rr.z));
      y.w = f2b(acc[mf][nf][3] + bb.w + b2f(rr.w));
      *(ushort4*)(outb + (size_t)grow * DIM + col0) = y;
    }
  }
}

// ---- 128x128 bf16 MFMA GEMM, BK=32, triple-ring (small GEMMs: mt, qk) -------
template <bool SWAPPED>
__device__ __forceinline__ void gemm128r(const u16* __restrict__ Ag, int lda,
                                         const u16* __restrict__ Bg, int ldb,
                                         int K, f32x4 acc[4][4]) {
  __shared__ __align__(16) u16 lA[3][4096];
  __shared__ __align__(16) u16 lB[3][4096];
  const int tid = threadIdx.x;
  const int lane = tid & 63;
  const int wave = tid >> 6;
  const int wm = wave >> 1, wn = wave & 1;
  const int rl = lane & 15;
  const int gc = ((tid & 3) ^ ((tid >> 3) & 3)) * 8;
  const int hs = ((lane >> 4) ^ ((rl >> 1) & 3)) * 8;
  const u16* a0 = Ag + (size_t)(tid >> 2) * lda + gc;
  const u16* a1 = a0 + (size_t)64 * lda;
  const u16* b0 = Bg + (size_t)(tid >> 2) * ldb + gc;
  const u16* b1 = b0 + (size_t)64 * ldb;
  const int ao = (wm * 64 + rl) * 32 + hs;
  const int bo = (wn * 64 + rl) * 32 + hs;
  const int nst = K >> 5;
  GLOAD16(a0, &lA[0][tid * 8]);
  GLOAD16(a1, &lA[0][2048 + tid * 8]);
  GLOAD16(b0, &lB[0][tid * 8]);
  GLOAD16(b1, &lB[0][2048 + tid * 8]);
  GLOAD16(a0 + 32, &lA[1][tid * 8]);
  GLOAD16(a1 + 32, &lA[1][2048 + tid * 8]);
  GLOAD16(b0 + 32, &lB[1][tid * 8]);
  GLOAD16(b1 + 32, &lB[1][2048 + tid * 8]);
  asm volatile("s_waitcnt vmcnt(4)" ::: "memory");
  __builtin_amdgcn_s_barrier();
  __builtin_amdgcn_sched_barrier(0);
  for (int k = 0; k < nst; ++k) {
    const int cur = k % 3;
    if (k + 2 < nst) {
      const int off = (k + 2) * 32;
      const int nb = (k + 2) % 3;
      GLOAD16(a0 + off, &lA[nb][tid * 8]);
      GLOAD16(a1 + off, &lA[nb][2048 + tid * 8]);
      GLOAD16(b0 + off, &lB[nb][tid * 8]);
      GLOAD16(b1 + off, &lB[nb][2048 + tid * 8]);
    }
    short8 af[4], bf[4];
#pragma unroll
    for (int i = 0; i < 4; i++) {
      af[i] = *(const short8*)&lA[cur][ao + i * 512];
      bf[i] = *(const short8*)&lB[cur][bo + i * 512];
    }
    __builtin_amdgcn_s_setprio(1);
    if (SWAPPED) {
#pragma unroll
      for (int mi = 0; mi < 4; mi++)
#pragma unroll
        for (int ni = 0; ni < 4; ni++)
          acc[mi][ni] = __builtin_amdgcn_mfma_f32_16x16x32_bf16(bf[ni], af[mi],
                                                                acc[mi][ni], 0, 0, 0);
    } else {
#pragma unroll
      for (int mi = 0; mi < 4; mi++)
#pragma unroll
        for (int ni = 0; ni < 4; ni++)
          acc[mi][ni] = __builtin_amdgcn_mfma_f32_16x16x32_bf16(af[mi], bf[ni],
                                                                acc[mi][ni], 0, 0, 0);
    }
    __builtin_amdgcn_s_setprio(0);
    if (k + 2 < nst) asm volatile("s_waitcnt vmcnt(4)" ::: "memory");
    else             asm volatile("s_waitcnt vmcnt(0)" ::: "memory");
    __builtin_amdgcn_s_barrier();
    __builtin_amdgcn_sched_barrier(0);
  }
}

// ---------------- MT[t] = kw[t] @ qw[t]^T  (bf16 out) ------------------------
__global__ __launch_bounds__(256) void k_gemm_mt(const u16* __restrict__ kwb,
                                                 const u16* __restrict__ qwb,
                                                 u16* __restrict__ mt) {
  int t = blockIdx.z;
  int m0 = blockIdx.y * 128, n0 = blockIdx.x * 128;
  f32x4 acc[4][4] = {};
  gemm128r<true>(kwb + (size_t)t * D2 + (size_t)m0 * DIM, DIM,
                 qwb + (size_t)t * D2 + (size_t)n0 * DIM, DIM, DIM, acc);
  const int lane = threadIdx.x & 63, wave = threadIdx.x >> 6;
  const int rl = lane & 15, c4 = (lane >> 4) * 4;
  const int wm = wave >> 1, wn = wave & 1;
#pragma unroll
  for (int mf = 0; mf < 4; mf++) {
    int row = m0 + wm * 64 + mf * 16 + rl;
#pragma unroll
    for (int nf = 0; nf < 4; nf++) {
      int col0 = n0 + wn * 64 + nf * 16 + c4;
      ushort4 y = { f2b(acc[mf][nf][0]), f2b(acc[mf][nf][1]),
                    f2b(acc[mf][nf][2]), f2b(acc[mf][nf][3]) };
      *(ushort4*)(mt + (size_t)t * D2 + (size_t)row * DIM + col0) = y;
    }
  }
}

// ------------- qkb[t] = bf16(x[t] @ MT[t]^T + kwqb[t]) -----------------------
__global__ __launch_bounds__(256) void k_gemm_qk(const u16* __restrict__ tib,
                                                 const u16* __restrict__ mt,
                                                 const float* __restrict__ kwqb,
                                                 u16* __restrict__ qkb) {
  int t = blockIdx.z;
  int m0 = blockIdx.y * 128, n0 = blockIdx.x * 128;
  f32x4 acc[4][4] = {};
  gemm128r<true>(tib + (size_t)t * BD + (size_t)m0 * DIM, DIM,
                 mt + (size_t)t * D2 + (size_t)n0 * DIM, DIM, DIM, acc);
  const int lane = threadIdx.x & 63, wave = threadIdx.x >> 6;
  const int rl = lane & 15, c4 = (lane >> 4) * 4;
  const int wm = wave >> 1, wn = wave & 1;
#pragma unroll
  for (int mf = 0; mf < 4; mf++) {
    int row = m0 + wm * 64 + mf * 16 + rl;
#pragma unroll
    for (int nf = 0; nf < 4; nf++) {
      int col0 = n0 + wn * 64 + nf * 16 + c4;
      float4 bb = *(const float4*)(kwqb + (size_t)t * DIM + col0);
      ushort4 y;
      y.x = f2b(acc[mf][nf][0] + bb.x);
      y.y = f2b(acc[mf][nf][1] + bb.y);
      y.z = f2b(acc[mf][nf][2] + bb.z);
      y.w = f2b(acc[mf][nf][3] + bb.w);
      *(ushort4*)(qkb + (size_t)t * BD + (size_t)row * DIM + col0) = y;
    }
  }
}

// ---- fused LN + scores + softmax + gating (one wave per (t,b)) --------------
__global__ __launch_bounds__(256) void k_score(const u16* __restrict__ stk16,
                                               const u16* __restrict__ qkb,
                                               const float* __restrict__ sbias,
                                               const float* __restrict__ sg,
                                               const float* __restrict__ sbt,
                                               const float* __restrict__ tg,
                                               const float* __restrict__ tbt,
                                               float* __restrict__ stacked,
                                               float* __restrict__ gated,
                                               float* __restrict__ wout) {
  int gw = (blockIdx.x * 256 + threadIdx.x) >> 6;
  int lane = threadIdx.x & 63;
  int b = gw & (BB - 1), t = gw >> 12;
  int d0 = lane * 8;
  size_t rowoff = ((size_t)t * BB + b) * DIM + d0;
  float qr[8];
  {
    ushort4 q0 = *(const ushort4*)(qkb + rowoff);
    ushort4 q1 = *(const ushort4*)(qkb + rowoff + 4);
    qr[0] = b2f(q0.x); qr[1] = b2f(q0.y); qr[2] = b2f(q0.z); qr[3] = b2f(q0.w);
    qr[4] = b2f(q1.x); qr[5] = b2f(q1.y); qr[6] = b2f(q1.z); qr[7] = b2f(q1.w);
  }
  float stv[8][8];
  float dots[8];
#pragma unroll
  for (int n = 0; n < 8; n++) {
    int e = (n < 4) ? n : (4 + t * 4 + (n - 4));
    const u16* sp = stk16 + ((size_t)e * BB + b) * DIM + d0;
    ushort4 v0 = *(const ushort4*)sp;
    ushort4 v1 = *(const ushort4*)(sp + 4);
    float v[8] = { b2f(v0.x), b2f(v0.y), b2f(v0.z), b2f(v0.w),
                   b2f(v1.x), b2f(v1.y), b2f(v1.z), b2f(v1.w) };
    float S = 0, Q = 0;
#pragma unroll
    for (int j = 0; j < 8; j++) { S += v[j]; Q += v[j] * v[j]; }
    S = wsum(S); Q = wsum(Q);
    float mu = S * (1.0f / DIM);
    float var = Q * (1.0f / DIM) - mu * mu;
    float rs = rsqrtf(var + 1e-5f);
    const float* gp; const float* bp;
    if (n < 4) { gp = sg + (size_t)n * DIM; bp = sbt + (size_t)n * DIM; }
    else {
      int te = t * 4 + (n - 4);
      gp = tg + (size_t)te * DIM; bp = tbt + (size_t)te * DIM;
    }
    float4 g0 = *(const float4*)(gp + d0), g1 = *(const float4*)(gp + d0 + 4);
    float4 b0 = *(const float4*)(bp + d0), b1 = *(const float4*)(bp + d0 + 4);
    float gv[8] = { g0.x, g0.y, g0.z, g0.w, g1.x, g1.y, g1.z, g1.w };
    float bv[8] = { b0.x, b0.y, b0.z, b0.w, b1.x, b1.y, b1.z, b1.w };
    float dd = 0;
#pragma unroll
    for (int j = 0; j < 8; j++) {
      float y = (v[j] - mu) * rs * gv[j] + bv[j];
      stv[n][j] = y;
      dd += y * qr[j];
    }
    float* so = stacked + (((size_t)t * 8 + n) * BB + b) * DIM + d0;
    *(float4*)so = *(float4*)&stv[n][0];
    *(float4*)(so + 4) = *(float4*)&stv[n][4];
    dots[n] = wsum(dd);
  }
  float sb = sbias[(size_t)t * BB + b];
  const float inv = 0.04419417382415922f;  // 1/sqrt(512)
  float sc[8], e[8];
  float mx = -1e30f;
#pragma unroll
  for (int n = 0; n < 8; n++) { sc[n] = (dots[n] + sb) * inv; mx = fmaxf(mx, sc[n]); }
  float den = 0;
#pragma unroll
  for (int n = 0; n < 8; n++) { e[n] = expf(sc[n] - mx); den += e[n]; }
  float rden = 1.0f / den;
  float wv[8];
#pragma unroll
  for (int n = 0; n < 8; n++) wv[n] = e[n] * rden;
  float wsel = 0;
#pragma unroll
  for (int n = 0; n < 8; n++) wsel = (lane == n) ? wv[n] : wsel;
  if (lane < 8) wout[((size_t)t * BB + b) * 8 + lane] = wsel;
  float g[8];
#pragma unroll
  for (int j = 0; j < 8; j++) {
    float s = 0;
#pragma unroll
    for (int n = 0; n < 8; n++) s += wv[n] * stv[n][j];
    g[j] = s;
  }
  float* go = gated + rowoff;
  *(float4*)(go) = *(float4*)&g[0];
  *(float4*)(go + 4) = *(float4*)&g[4];
}

// ============================ host launcher ==================================
extern "C" void kernel_launch(void* const* d_in, const int* in_sizes, int n_in,
                              void* d_out, int out_size, void* d_ws, size_t ws_size,
                              hipStream_t stream) {
  const float* ti  = (const float*)d_in[0];
  const float* sw1 = (const float*)d_in[1];
  const float* sb1 = (const float*)d_in[2];
  const float* sw2 = (const float*)d_in[3];
  const float* sb2 = (const float*)d_in[4];
  const float* sg  = (const float*)d_in[5];
  const float* sbt = (const float*)d_in[6];
  const float* tw1 = (const float*)d_in[7];
  const float* tb1 = (const float*)d_in[8];
  const float* tw2 = (const float*)d_in[9];
  const float* tb2 = (const float*)d_in[10];
  const float* tg  = (const float*)d_in[11];
  const float* tbt = (const float*)d_in[12];
  const float* qw  = (const float*)d_in[13];
  const float* qb  = (const float*)d_in[14];
  const float* kw  = (const float*)d_in[15];
  const float* kb  = (const float*)d_in[16];

  float* out = (float*)d_out;
  float* gated   = out;                                   // T*B*D
  float* weights = out + (size_t)TT * BB * DIM;           // T*B*8
  float* stacked = weights + (size_t)TT * BB * 8;         // T*8*B*D

  char* ws = (char*)d_ws;
  u16*   tib   = (u16*)(ws);                    // 16,777,216
  u16*   xsb   = (u16*)(ws + 16777216);         //  4,194,304
  u16*   w1t   = (u16*)(ws + 20971520);         // 20,971,520
  u16*   w2t   = (u16*)(ws + 41943040);         // 20,971,520
  u16*   qwb   = (u16*)(ws + 62914560);         //  2,097,152
  u16*   kwb   = (u16*)(ws + 65011712);         //  2,097,152
  u16*   mt    = (u16*)(ws + 67108864);         //  2,097,152
  float* sbias = (float*)(ws + 69206016);       //     65,536
  float* qwkb  = (float*)(ws + 69271552);       //      8,192
  float* kwqb  = (float*)(ws + 69279744);       //      8,192
  float* kbqb  = (float*)(ws + 69287936);       //      1,024
  u16*   qkb   = (u16*)(ws + 69288960);         // 16,777,216
  u16*   stk16 = (u16*)(ws + 86066176);         // 83,886,080 (20*B*D bf16)
  u16*   hbuf  = (u16*)(ws + 169952256);        // SR*HDIM*2*20

  const size_t hoff = 169952256;
  int SR = 512;
  if (ws_size >= hoff + (size_t)NEXP * BB * HDIM * 2) SR = BB;           // 338 MB
  else if (ws_size >= hoff + (size_t)NEXP * 1024 * HDIM * 2) SR = 1024;

  // weight / gate preprocessing
  k_tcast<<<dim3(32, 16, 4), 256, 0, stream>>>(sw1, w1t, DIM, HDIM);
  k_tcast<<<dim3(32, 16, 16), 256, 0, stream>>>(tw1, w1t + (size_t)4 * HDIM * DIM, DIM, HDIM);
  k_tcast<<<dim3(16, 32, 4), 256, 0, stream>>>(sw2, w2t, HDIM, DIM);
  k_tcast<<<dim3(16, 32, 16), 256, 0, stream>>>(tw2, w2t + (size_t)4 * DIM * HDIM, HDIM, DIM);
  k_cast<<<1024, 256, 0, stream>>>(qw, qwb);
  k_cast<<<1024, 256, 0, stream>>>(kw, kwb);
  k_biasvec<<<1025, 256, 0, stream>>>(qw, kb, kw, qb, qwkb, kwqb, kbqb);
  k_prep<<<1024, 256, 0, stream>>>(ti, qwkb, kbqb, tib, xsb, sbias);
  k_gemm_mt<<<dim3(4, 4, 4), 256, 0, stream>>>(kwb, qwb, mt);

  // expert FFNs: 256x256 tiles, BK=32 triple-ring counted-vmcnt pipeline
  for (int row0 = 0; row0 < BB; row0 += SR) {
    k_gemm_up<<<dim3(4, SR / 256, NEXP), 512, 0, stream>>>(xsb, tib, w1t, sb1, tb1,
                                                           hbuf, row0, SR);
    k_gemm_down<<<dim3(2, SR / 256, NEXP), 512, 0, stream>>>(hbuf, w2t, sb2, tb2,
                                                             xsb, tib, stk16, row0, SR);
  }

  k_gemm_qk<<<dim3(4, 32, 4), 256, 0, stream>>>(tib, mt, kwqb, qkb);
  k_score<<<4096, 256, 0, stream>>>(stk16, qkb, sbias, sg, sbt, tg, tbt,
                                    stacked, gated, weights);
}

// Round 17
// 500.147 us; speedup vs baseline: 1.1114x; 1.1114x over previous
//
#include <hip/hip_runtime.h>
#include <math.h>

typedef unsigned short u16;
typedef short short8 __attribute__((ext_vector_type(8)));
typedef float f32x4 __attribute__((ext_vector_type(4)));

#define TT 4
#define BB 4096
#define DIM 512
#define HDIM 1024
#define BD (BB*DIM)      // 2097152
#define D2 (DIM*DIM)     // 262144
#define NEXP 20

#define GLOAD16(gp, lp) __builtin_amdgcn_global_load_lds( \
    (__attribute__((address_space(1))) void*)(void*)(gp), \
    (__attribute__((address_space(3))) void*)(void*)(lp), 16, 0, 0)

__device__ __forceinline__ u16 f2b(float f) {
  union { float f; unsigned u; } x; x.f = f;
  unsigned r = x.u + 0x7FFFu + ((x.u >> 16) & 1u);
  return (u16)(r >> 16);
}
__device__ __forceinline__ float b2f(u16 v) {
  union { unsigned u; float f; } x; x.u = ((unsigned)v) << 16; return x.f;
}

__device__ __forceinline__ float wsum(float v) {
#pragma unroll
  for (int o = 32; o > 0; o >>= 1) v += __shfl_xor(v, o);
  return v;
}

// fast exact-enough GELU
__device__ __forceinline__ float fgelu(float v) {
  float u = 1.5957691216057308f * v * (1.0f + 0.044715f * v * v);
  return v / (1.0f + __expf(-u));
}

// ------ prep: one wave per row b: mean, bf16 casts, score-bias sbias --------
__global__ __launch_bounds__(256) void k_prep(const float* __restrict__ ti,
                                              const float* __restrict__ qwkb,
                                              const float* __restrict__ kbqb,
                                              u16* __restrict__ tib,
                                              u16* __restrict__ xsb,
                                              float* __restrict__ sbias) {
  int gw = (blockIdx.x * 256 + threadIdx.x) >> 6;   // row b
  int lane = threadIdx.x & 63;
  int d0 = lane * 8;
  float x[4][8];
#pragma unroll
  for (int t = 0; t < 4; t++) {
    const float* p = ti + ((size_t)t * BB + gw) * DIM + d0;
    *(float4*)&x[t][0] = *(const float4*)p;
    *(float4*)&x[t][4] = *(const float4*)(p + 4);
  }
  float m[8];
#pragma unroll
  for (int j = 0; j < 8; j++)
    m[j] = (x[0][j] + x[1][j] + x[2][j] + x[3][j]) * 0.25f;
#pragma unroll
  for (int t = 0; t < 4; t++) {
    ushort4 c0 = { f2b(x[t][0]), f2b(x[t][1]), f2b(x[t][2]), f2b(x[t][3]) };
    ushort4 c1 = { f2b(x[t][4]), f2b(x[t][5]), f2b(x[t][6]), f2b(x[t][7]) };
    u16* q = tib + ((size_t)t * BB + gw) * DIM + d0;
    *(ushort4*)q = c0; *(ushort4*)(q + 4) = c1;
  }
  {
    ushort4 c0 = { f2b(m[0]), f2b(m[1]), f2b(m[2]), f2b(m[3]) };
    ushort4 c1 = { f2b(m[4]), f2b(m[5]), f2b(m[6]), f2b(m[7]) };
    u16* q = xsb + (size_t)gw * DIM + d0;
    *(ushort4*)q = c0; *(ushort4*)(q + 4) = c1;
  }
#pragma unroll
  for (int t = 0; t < 4; t++) {
    const float* wp = qwkb + (size_t)t * DIM + d0;
    float4 w0 = *(const float4*)wp, w1 = *(const float4*)(wp + 4);
    float s = x[t][0]*w0.x + x[t][1]*w0.y + x[t][2]*w0.z + x[t][3]*w0.w
            + x[t][4]*w1.x + x[t][5]*w1.y + x[t][6]*w1.z + x[t][7]*w1.w;
    s = wsum(s);
    if (lane == 0) sbias[(size_t)t * BB + gw] = s + kbqb[t];
  }
}

// ------------- batched transpose+cast: (G,R,C) f32 -> (G,C,R) bf16 -----------
__global__ __launch_bounds__(256) void k_tcast(const float* __restrict__ in,
                                               u16* __restrict__ out,
                                               int R, int C) {
  __shared__ float tile[32][33];
  size_t gb = (size_t)blockIdx.z * R * C;
  in += gb; out += gb;
  int c0 = blockIdx.x * 32, r0 = blockIdx.y * 32;
  int tx = threadIdx.x & 31, ty = threadIdx.x >> 5;
#pragma unroll
  for (int j = 0; j < 4; j++)
    tile[ty + j * 8][tx] = in[(size_t)(r0 + ty + j * 8) * C + c0 + tx];
  __syncthreads();
#pragma unroll
  for (int j = 0; j < 4; j++)
    out[(size_t)(c0 + ty + j * 8) * R + r0 + tx] = f2b(tile[tx][ty + j * 8]);
}

// ---------------- plain cast f32 -> bf16 -------------------------------------
__global__ __launch_bounds__(256) void k_cast(const float* __restrict__ in,
                                              u16* __restrict__ out) {
  size_t i = ((size_t)blockIdx.x * 256 + threadIdx.x) * 4;
  float4 v = *(const float4*)(in + i);
  ushort4 b = { f2b(v.x), f2b(v.y), f2b(v.z), f2b(v.w) };
  *(ushort4*)(out + i) = b;
}

// --------------- small bias-vector precomputes -------------------------------
__global__ __launch_bounds__(256) void k_biasvec(const float* __restrict__ qw,
                                                 const float* __restrict__ kb,
                                                 const float* __restrict__ kw,
                                                 const float* __restrict__ qb,
                                                 float* __restrict__ qwkb,
                                                 float* __restrict__ kwqb,
                                                 float* __restrict__ kbqb) {
  int gw = (blockIdx.x * 256 + threadIdx.x) >> 6;
  int lane = threadIdx.x & 63;
  if (gw < 2048) {
    int t = gw >> 9, c = gw & 511;
    const float* row = qw + ((size_t)t * DIM + c) * DIM;
    const float* v = kb + (size_t)t * DIM;
    float s = 0;
#pragma unroll
    for (int j = 0; j < 8; j++) s += row[lane * 8 + j] * v[lane * 8 + j];
    s = wsum(s);
    if (lane == 0) qwkb[(size_t)t * DIM + c] = s;
  } else if (gw < 4096) {
    int t = (gw - 2048) >> 9, d = gw & 511;
    const float* row = kw + ((size_t)t * DIM + d) * DIM;
    const float* v = qb + (size_t)t * DIM;
    float s = 0;
#pragma unroll
    for (int j = 0; j < 8; j++) s += row[lane * 8 + j] * v[lane * 8 + j];
    s = wsum(s);
    if (lane == 0) kwqb[(size_t)t * DIM + d] = s;
  } else if (gw < 4100) {
    int t = gw - 4096;
    const float* a = kb + (size_t)t * DIM;
    const float* c = qb + (size_t)t * DIM;
    float s = 0;
#pragma unroll
    for (int j = 0; j < 8; j++) s += a[lane * 8 + j] * c[lane * 8 + j];
    s = wsum(s);
    if (lane == 0) kbqb[t] = s;
  }
}

// ---- 256x128 bf16 MFMA GEMM, 512 thr, BK=32, triple-ring counted vmcnt ------
// 85 FLOP/byte staged; 72 KB LDS -> 2 blocks/CU.
// Per thread per tile: 3 loads (2 A + 1 B); end-of-iter vmcnt(3) keeps tile
// k+2 in flight across the barrier (never drains in the main loop).
template <bool SWAPPED>
__device__ __forceinline__ void gemmBigr(const u16* __restrict__ Ag, int lda,
                                         const u16* __restrict__ Bg, int ldb,
                                         int K, f32x4 acc[4][4]) {
  __shared__ __align__(16) u16 lA[3][8192];   // 3 x (256 x 32)
  __shared__ __align__(16) u16 lB[3][4096];   // 3 x (128 x 32)
  const int tid = threadIdx.x;                // 0..511
  const int lane = tid & 63;
  const int wave = tid >> 6;                  // 0..7
  const int wm = wave >> 1, wn = wave & 1;    // 4 x 2 wave grid, 64x64 tiles
  const int rl = lane & 15;
  const int row = tid >> 2;                   // 0..127
  const int gc = ((tid & 3) ^ ((row >> 1) & 3)) * 8;    // pre-swizzled chunk
  const int hs = (((lane >> 4) ^ ((rl >> 1) & 3))) * 8; // swizzled read chunk
  const u16* a0 = Ag + (size_t)row * lda + gc;          // A rows 0..127
  const u16* a1 = a0 + (size_t)128 * lda;               // A rows 128..255
  const u16* b0 = Bg + (size_t)row * ldb + gc;          // B rows 0..127
  const int ao = (wm * 64 + rl) * 32 + hs;
  const int bo = (wn * 64 + rl) * 32 + hs;
  const int nst = K >> 5;
  // prologue: stage tiles 0 and 1
  GLOAD16(a0, &lA[0][tid * 8]);
  GLOAD16(a1, &lA[0][4096 + tid * 8]);
  GLOAD16(b0, &lB[0][tid * 8]);
  GLOAD16(a0 + 32, &lA[1][tid * 8]);
  GLOAD16(a1 + 32, &lA[1][4096 + tid * 8]);
  GLOAD16(b0 + 32, &lB[1][tid * 8]);
  asm volatile("s_waitcnt vmcnt(3)" ::: "memory");  // tile0 landed
  __builtin_amdgcn_s_barrier();
  __builtin_amdgcn_sched_barrier(0);
  for (int k = 0; k < nst; ++k) {
    const int cur = k % 3;
    if (k + 2 < nst) {                   // issue tile k+2 into ring slot
      const int off = (k + 2) * 32;
      const int nb = (k + 2) % 3;
      GLOAD16(a0 + off, &lA[nb][tid * 8]);
      GLOAD16(a1 + off, &lA[nb][4096 + tid * 8]);
      GLOAD16(b0 + off, &lB[nb][tid * 8]);
    }
    short8 af[4], bf[4];
#pragma unroll
    for (int i = 0; i < 4; i++) {
      af[i] = *(const short8*)&lA[cur][ao + i * 512];
      bf[i] = *(const short8*)&lB[cur][bo + i * 512];
    }
    __builtin_amdgcn_s_setprio(1);
    if (SWAPPED) {
#pragma unroll
      for (int mi = 0; mi < 4; mi++)
#pragma unroll
        for (int ni = 0; ni < 4; ni++)
          acc[mi][ni] = __builtin_amdgcn_mfma_f32_16x16x32_bf16(bf[ni], af[mi],
                                                                acc[mi][ni], 0, 0, 0);
    } else {
#pragma unroll
      for (int mi = 0; mi < 4; mi++)
#pragma unroll
        for (int ni = 0; ni < 4; ni++)
          acc[mi][ni] = __builtin_amdgcn_mfma_f32_16x16x32_bf16(af[mi], bf[ni],
                                                                acc[mi][ni], 0, 0, 0);
    }
    __builtin_amdgcn_s_setprio(0);
    // counted wait: tile k+1 landed; tile k+2 (3 loads) stays in flight
    if (k + 2 < nst) asm volatile("s_waitcnt vmcnt(3)" ::: "memory");
    else             asm volatile("s_waitcnt vmcnt(0)" ::: "memory");
    __builtin_amdgcn_s_barrier();
    __builtin_amdgcn_sched_barrier(0);
  }
}

// ---------------- expert up-GEMM: h = gelu(x@W1 + b1), bf16 out --------------
// 256x128 tile, non-swapped epilogue: row=(lane>>4)*4+r, col=lane&15.
__global__ __launch_bounds__(512, 4) void k_gemm_up(const u16* __restrict__ xsb,
                                                 const u16* __restrict__ tib,
                                                 const u16* __restrict__ w1t,
                                                 const float* __restrict__ sb1,
                                                 const float* __restrict__ tb1,
                                                 u16* __restrict__ hbuf,
                                                 int row0, int SR) {
  int ge = blockIdx.z;
  const u16* A;
  const float* bias;
  if (ge < 4) { A = xsb; bias = sb1 + (size_t)ge * HDIM; }
  else {
    int te = ge - 4;
    A = tib + (size_t)(te >> 2) * BD;
    bias = tb1 + (size_t)te * HDIM;
  }
  A += (size_t)row0 * DIM;
  const u16* W = w1t + (size_t)ge * ((size_t)HDIM * DIM);
  int m0 = blockIdx.y * 256, n0 = blockIdx.x * 128;
  f32x4 acc[4][4] = {};
  gemmBigr<false>(A + (size_t)m0 * DIM, DIM, W + (size_t)n0 * DIM, DIM, DIM, acc);
  u16* out = hbuf + (size_t)ge * ((size_t)SR * HDIM);
  const int lane = threadIdx.x & 63, wave = threadIdx.x >> 6;
  const int rbase = m0 + (wave >> 1) * 64 + (lane >> 4) * 4;
  const int cbase = n0 + (wave & 1) * 64 + (lane & 15);
#pragma unroll
  for (int mi = 0; mi < 4; mi++)
#pragma unroll
    for (int ni = 0; ni < 4; ni++)
#pragma unroll
      for (int r = 0; r < 4; r++) {
        int row = rbase + mi * 16 + r;
        int col = cbase + ni * 16;
        float v = acc[mi][ni][r] + bias[col];
        out[(size_t)row * HDIM + col] = f2b(fgelu(v));
      }
}

// ---- down-GEMM: preLN bf16 = h@W2 + b2 + residual -> stk16[20][B][D] --------
// 256x128 tile, swapped epilogue: lane owns (row=rl, 4 cols) -> ushort4.
__global__ __launch_bounds__(512, 4) void k_gemm_down(const u16* __restrict__ hbuf,
                                                   const u16* __restrict__ w2t,
                                                   const float* __restrict__ sb2,
                                                   const float* __restrict__ tb2,
                                                   const u16* __restrict__ xsb,
                                                   const u16* __restrict__ tib,
                                                   u16* __restrict__ stk16,
                                                   int row0, int SR) {
  int ge = blockIdx.z;
  int m0 = blockIdx.y * 256, n0 = blockIdx.x * 128;
  const u16* Ag = hbuf + (size_t)ge * ((size_t)SR * HDIM) + (size_t)m0 * HDIM;
  const u16* Bg = w2t + (size_t)ge * ((size_t)DIM * HDIM) + (size_t)n0 * HDIM;
  f32x4 acc[4][4] = {};
  gemmBigr<true>(Ag, HDIM, Bg, HDIM, HDIM, acc);
  const float* bias; const u16* resb;
  int te = ge - 4;
  if (ge < 4) { bias = sb2 + (size_t)ge * DIM; resb = xsb; }
  else { bias = tb2 + (size_t)te * DIM; resb = tib + (size_t)(te >> 2) * BD; }
  const int lane = threadIdx.x & 63, wave = threadIdx.x >> 6;
  const int rl = lane & 15, c4 = (lane >> 4) * 4;
  const int wm = wave >> 1, wn = wave & 1;
  u16* outb = stk16 + (size_t)ge * BD;
#pragma unroll
  for (int mf = 0; mf < 4; mf++) {
    int grow = row0 + m0 + wm * 64 + mf * 16 + rl;
#pragma unroll
    for (int nf = 0; nf < 4; nf++) {
      int col0 = n0 + wn * 64 + nf * 16 + c4;
      float4 bb = *(const float4*)(bias + col0);
      ushort4 rr = *(const ushort4*)(resb + (size_t)grow * DIM + col0);
      ushort4 y;
      y.x = f2b(acc[mf][nf][0] + bb.x + b2f(rr.x));
      y.y = f2b(acc[mf][nf][1] + bb.y + b2f(rr.y));
      y.z = f2b(acc[mf][nf][2] + bb.z + b2f(rr.z));
      y.w = f2b(acc[mf][nf][3] + bb.w + b2f(rr.w));
      *(ushort4*)(outb + (size_t)grow * DIM + col0) = y;
    }
  }
}

// ---- 128x128 bf16 MFMA GEMM, BK=32, triple-ring (small GEMMs: mt, qk) -------
template <bool SWAPPED>
__device__ __forceinline__ void gemm128r(const u16* __restrict__ Ag, int lda,
                                         const u16* __restrict__ Bg, int ldb,
                                         int K, f32x4 acc[4][4]) {
  __shared__ __align__(16) u16 lA[3][4096];
  __shared__ __align__(16) u16 lB[3][4096];
  const int tid = threadIdx.x;
  const int lane = tid & 63;
  const int wave = tid >> 6;
  const int wm = wave >> 1, wn = wave & 1;
  const int rl = lane & 15;
  const int gc = ((tid & 3) ^ ((tid >> 3) & 3)) * 8;
  const int hs = ((lane >> 4) ^ ((rl >> 1) & 3)) * 8;
  const u16* a0 = Ag + (size_t)(tid >> 2) * lda + gc;
  const u16* a1 = a0 + (size_t)64 * lda;
  const u16* b0 = Bg + (size_t)(tid >> 2) * ldb + gc;
  const u16* b1 = b0 + (size_t)64 * ldb;
  const int ao = (wm * 64 + rl) * 32 + hs;
  const int bo = (wn * 64 + rl) * 32 + hs;
  const int nst = K >> 5;
  GLOAD16(a0, &lA[0][tid * 8]);
  GLOAD16(a1, &lA[0][2048 + tid * 8]);
  GLOAD16(b0, &lB[0][tid * 8]);
  GLOAD16(b1, &lB[0][2048 + tid * 8]);
  GLOAD16(a0 + 32, &lA[1][tid * 8]);
  GLOAD16(a1 + 32, &lA[1][2048 + tid * 8]);
  GLOAD16(b0 + 32, &lB[1][tid * 8]);
  GLOAD16(b1 + 32, &lB[1][2048 + tid * 8]);
  asm volatile("s_waitcnt vmcnt(4)" ::: "memory");
  __builtin_amdgcn_s_barrier();
  __builtin_amdgcn_sched_barrier(0);
  for (int k = 0; k < nst; ++k) {
    const int cur = k % 3;
    if (k + 2 < nst) {
      const int off = (k + 2) * 32;
      const int nb = (k + 2) % 3;
      GLOAD16(a0 + off, &lA[nb][tid * 8]);
      GLOAD16(a1 + off, &lA[nb][2048 + tid * 8]);
      GLOAD16(b0 + off, &lB[nb][tid * 8]);
      GLOAD16(b1 + off, &lB[nb][2048 + tid * 8]);
    }
    short8 af[4], bf[4];
#pragma unroll
    for (int i = 0; i < 4; i++) {
      af[i] = *(const short8*)&lA[cur][ao + i * 512];
      bf[i] = *(const short8*)&lB[cur][bo + i * 512];
    }
    __builtin_amdgcn_s_setprio(1);
    if (SWAPPED) {
#pragma unroll
      for (int mi = 0; mi < 4; mi++)
#pragma unroll
        for (int ni = 0; ni < 4; ni++)
          acc[mi][ni] = __builtin_amdgcn_mfma_f32_16x16x32_bf16(bf[ni], af[mi],
                                                                acc[mi][ni], 0, 0, 0);
    } else {
#pragma unroll
      for (int mi = 0; mi < 4; mi++)
#pragma unroll
        for (int ni = 0; ni < 4; ni++)
          acc[mi][ni] = __builtin_amdgcn_mfma_f32_16x16x32_bf16(af[mi], bf[ni],
                                                                acc[mi][ni], 0, 0, 0);
    }
    __builtin_amdgcn_s_setprio(0);
    if (k + 2 < nst) asm volatile("s_waitcnt vmcnt(4)" ::: "memory");
    else             asm volatile("s_waitcnt vmcnt(0)" ::: "memory");
    __builtin_amdgcn_s_barrier();
    __builtin_amdgcn_sched_barrier(0);
  }
}

// ---------------- MT[t] = kw[t] @ qw[t]^T  (bf16 out) ------------------------
__global__ __launch_bounds__(256) void k_gemm_mt(const u16* __restrict__ kwb,
                                                 const u16* __restrict__ qwb,
                                                 u16* __restrict__ mt) {
  int t = blockIdx.z;
  int m0 = blockIdx.y * 128, n0 = blockIdx.x * 128;
  f32x4 acc[4][4] = {};
  gemm128r<true>(kwb + (size_t)t * D2 + (size_t)m0 * DIM, DIM,
                 qwb + (size_t)t * D2 + (size_t)n0 * DIM, DIM, DIM, acc);
  const int lane = threadIdx.x & 63, wave = threadIdx.x >> 6;
  const int rl = lane & 15, c4 = (lane >> 4) * 4;
  const int wm = wave >> 1, wn = wave & 1;
#pragma unroll
  for (int mf = 0; mf < 4; mf++) {
    int row = m0 + wm * 64 + mf * 16 + rl;
#pragma unroll
    for (int nf = 0; nf < 4; nf++) {
      int col0 = n0 + wn * 64 + nf * 16 + c4;
      ushort4 y = { f2b(acc[mf][nf][0]), f2b(acc[mf][nf][1]),
                    f2b(acc[mf][nf][2]), f2b(acc[mf][nf][3]) };
      *(ushort4*)(mt + (size_t)t * D2 + (size_t)row * DIM + col0) = y;
    }
  }
}

// ------------- qkb[t] = bf16(x[t] @ MT[t]^T + kwqb[t]) -----------------------
__global__ __launch_bounds__(256) void k_gemm_qk(const u16* __restrict__ tib,
                                                 const u16* __restrict__ mt,
                                                 const float* __restrict__ kwqb,
                                                 u16* __restrict__ qkb) {
  int t = blockIdx.z;
  int m0 = blockIdx.y * 128, n0 = blockIdx.x * 128;
  f32x4 acc[4][4] = {};
  gemm128r<true>(tib + (size_t)t * BD + (size_t)m0 * DIM, DIM,
                 mt + (size_t)t * D2 + (size_t)n0 * DIM, DIM, DIM, acc);
  const int lane = threadIdx.x & 63, wave = threadIdx.x >> 6;
  const int rl = lane & 15, c4 = (lane >> 4) * 4;
  const int wm = wave >> 1, wn = wave & 1;
#pragma unroll
  for (int mf = 0; mf < 4; mf++) {
    int row = m0 + wm * 64 + mf * 16 + rl;
#pragma unroll
    for (int nf = 0; nf < 4; nf++) {
      int col0 = n0 + wn * 64 + nf * 16 + c4;
      float4 bb = *(const float4*)(kwqb + (size_t)t * DIM + col0);
      ushort4 y;
      y.x = f2b(acc[mf][nf][0] + bb.x);
      y.y = f2b(acc[mf][nf][1] + bb.y);
      y.z = f2b(acc[mf][nf][2] + bb.z);
      y.w = f2b(acc[mf][nf][3] + bb.w);
      *(ushort4*)(qkb + (size_t)t * BD + (size_t)row * DIM + col0) = y;
    }
  }
}

// ---- fused LN + scores + softmax + gating (one wave per (t,b)) --------------
__global__ __launch_bounds__(256) void k_score(const u16* __restrict__ stk16,
                                               const u16* __restrict__ qkb,
                                               const float* __restrict__ sbias,
                                               const float* __restrict__ sg,
                                               const float* __restrict__ sbt,
                                               const float* __restrict__ tg,
                                               const float* __restrict__ tbt,
                                               float* __restrict__ stacked,
                                               float* __restrict__ gated,
                                               float* __restrict__ wout) {
  int gw = (blockIdx.x * 256 + threadIdx.x) >> 6;
  int lane = threadIdx.x & 63;
  int b = gw & (BB - 1), t = gw >> 12;
  int d0 = lane * 8;
  size_t rowoff = ((size_t)t * BB + b) * DIM + d0;
  float qr[8];
  {
    ushort4 q0 = *(const ushort4*)(qkb + rowoff);
    ushort4 q1 = *(const ushort4*)(qkb + rowoff + 4);
    qr[0] = b2f(q0.x); qr[1] = b2f(q0.y); qr[2] = b2f(q0.z); qr[3] = b2f(q0.w);
    qr[4] = b2f(q1.x); qr[5] = b2f(q1.y); qr[6] = b2f(q1.z); qr[7] = b2f(q1.w);
  }
  float stv[8][8];
  float dots[8];
#pragma unroll
  for (int n = 0; n < 8; n++) {
    int e = (n < 4) ? n : (4 + t * 4 + (n - 4));
    const u16* sp = stk16 + ((size_t)e * BB + b) * DIM + d0;
    ushort4 v0 = *(const ushort4*)sp;
    ushort4 v1 = *(const ushort4*)(sp + 4);
    float v[8] = { b2f(v0.x), b2f(v0.y), b2f(v0.z), b2f(v0.w),
                   b2f(v1.x), b2f(v1.y), b2f(v1.z), b2f(v1.w) };
    float S = 0, Q = 0;
#pragma unroll
    for (int j = 0; j < 8; j++) { S += v[j]; Q += v[j] * v[j]; }
    S = wsum(S); Q = wsum(Q);
    float mu = S * (1.0f / DIM);
    float var = Q * (1.0f / DIM) - mu * mu;
    float rs = rsqrtf(var + 1e-5f);
    const float* gp; const float* bp;
    if (n < 4) { gp = sg + (size_t)n * DIM; bp = sbt + (size_t)n * DIM; }
    else {
      int te = t * 4 + (n - 4);
      gp = tg + (size_t)te * DIM; bp = tbt + (size_t)te * DIM;
    }
    float4 g0 = *(const float4*)(gp + d0), g1 = *(const float4*)(gp + d0 + 4);
    float4 b0 = *(const float4*)(bp + d0), b1 = *(const float4*)(bp + d0 + 4);
    float gv[8] = { g0.x, g0.y, g0.z, g0.w, g1.x, g1.y, g1.z, g1.w };
    float bv[8] = { b0.x, b0.y, b0.z, b0.w, b1.x, b1.y, b1.z, b1.w };
    float dd = 0;
#pragma unroll
    for (int j = 0; j < 8; j++) {
      float y = (v[j] - mu) * rs * gv[j] + bv[j];
      stv[n][j] = y;
      dd += y * qr[j];
    }
    float* so = stacked + (((size_t)t * 8 + n) * BB + b) * DIM + d0;
    *(float4*)so = *(float4*)&stv[n][0];
    *(float4*)(so + 4) = *(float4*)&stv[n][4];
    dots[n] = wsum(dd);
  }
  float sb = sbias[(size_t)t * BB + b];
  const float inv = 0.04419417382415922f;  // 1/sqrt(512)
  float sc[8], e[8];
  float mx = -1e30f;
#pragma unroll
  for (int n = 0; n < 8; n++) { sc[n] = (dots[n] + sb) * inv; mx = fmaxf(mx, sc[n]); }
  float den = 0;
#pragma unroll
  for (int n = 0; n < 8; n++) { e[n] = expf(sc[n] - mx); den += e[n]; }
  float rden = 1.0f / den;
  float wv[8];
#pragma unroll
  for (int n = 0; n < 8; n++) wv[n] = e[n] * rden;
  float wsel = 0;
#pragma unroll
  for (int n = 0; n < 8; n++) wsel = (lane == n) ? wv[n] : wsel;
  if (lane < 8) wout[((size_t)t * BB + b) * 8 + lane] = wsel;
  float g[8];
#pragma unroll
  for (int j = 0; j < 8; j++) {
    float s = 0;
#pragma unroll
    for (int n = 0; n < 8; n++) s += wv[n] * stv[n][j];
    g[j] = s;
  }
  float* go = gated + rowoff;
  *(float4*)(go) = *(float4*)&g[0];
  *(float4*)(go + 4) = *(float4*)&g[4];
}

// ============================ host launcher ==================================
extern "C" void kernel_launch(void* const* d_in, const int* in_sizes, int n_in,
                              void* d_out, int out_size, void* d_ws, size_t ws_size,
                              hipStream_t stream) {
  const float* ti  = (const float*)d_in[0];
  const float* sw1 = (const float*)d_in[1];
  const float* sb1 = (const float*)d_in[2];
  const float* sw2 = (const float*)d_in[3];
  const float* sb2 = (const float*)d_in[4];
  const float* sg  = (const float*)d_in[5];
  const float* sbt = (const float*)d_in[6];
  const float* tw1 = (const float*)d_in[7];
  const float* tb1 = (const float*)d_in[8];
  const float* tw2 = (const float*)d_in[9];
  const float* tb2 = (const float*)d_in[10];
  const float* tg  = (const float*)d_in[11];
  const float* tbt = (const float*)d_in[12];
  const float* qw  = (const float*)d_in[13];
  const float* qb  = (const float*)d_in[14];
  const float* kw  = (const float*)d_in[15];
  const float* kb  = (const float*)d_in[16];

  float* out = (float*)d_out;
  float* gated   = out;                                   // T*B*D
  float* weights = out + (size_t)TT * BB * DIM;           // T*B*8
  float* stacked = weights + (size_t)TT * BB * 8;         // T*8*B*D

  char* ws = (char*)d_ws;
  u16*   tib   = (u16*)(ws);                    // 16,777,216
  u16*   xsb   = (u16*)(ws + 16777216);         //  4,194,304
  u16*   w1t   = (u16*)(ws + 20971520);         // 20,971,520
  u16*   w2t   = (u16*)(ws + 41943040);         // 20,971,520
  u16*   qwb   = (u16*)(ws + 62914560);         //  2,097,152
  u16*   kwb   = (u16*)(ws + 65011712);         //  2,097,152
  u16*   mt    = (u16*)(ws + 67108864);         //  2,097,152
  float* sbias = (float*)(ws + 69206016);       //     65,536
  float* qwkb  = (float*)(ws + 69271552);       //      8,192
  float* kwqb  = (float*)(ws + 69279744);       //      8,192
  float* kbqb  = (float*)(ws + 69287936);       //      1,024
  u16*   qkb   = (u16*)(ws + 69288960);         // 16,777,216
  u16*   stk16 = (u16*)(ws + 86066176);         // 83,886,080 (20*B*D bf16)
  u16*   hbuf  = (u16*)(ws + 169952256);        // SR*HDIM*2*20

  const size_t hoff = 169952256;
  int SR = 512;
  if (ws_size >= hoff + (size_t)NEXP * BB * HDIM * 2) SR = BB;           // 338 MB
  else if (ws_size >= hoff + (size_t)NEXP * 1024 * HDIM * 2) SR = 1024;

  // weight / gate preprocessing
  k_tcast<<<dim3(32, 16, 4), 256, 0, stream>>>(sw1, w1t, DIM, HDIM);
  k_tcast<<<dim3(32, 16, 16), 256, 0, stream>>>(tw1, w1t + (size_t)4 * HDIM * DIM, DIM, HDIM);
  k_tcast<<<dim3(16, 32, 4), 256, 0, stream>>>(sw2, w2t, HDIM, DIM);
  k_tcast<<<dim3(16, 32, 16), 256, 0, stream>>>(tw2, w2t + (size_t)4 * DIM * HDIM, HDIM, DIM);
  k_cast<<<1024, 256, 0, stream>>>(qw, qwb);
  k_cast<<<1024, 256, 0, stream>>>(kw, kwb);
  k_biasvec<<<1025, 256, 0, stream>>>(qw, kb, kw, qb, qwkb, kwqb, kbqb);
  k_prep<<<1024, 256, 0, stream>>>(ti, qwkb, kbqb, tib, xsb, sbias);
  k_gemm_mt<<<dim3(4, 4, 4), 256, 0, stream>>>(kwb, qwb, mt);

  // expert FFNs: 256x128 tiles, BK=32 triple-ring counted-vmcnt pipeline
  for (int row0 = 0; row0 < BB; row0 += SR) {
    k_gemm_up<<<dim3(8, SR / 256, NEXP), 512, 0, stream>>>(xsb, tib, w1t, sb1, tb1,
                                                           hbuf, row0, SR);
    k_gemm_down<<<dim3(4, SR / 256, NEXP), 512, 0, stream>>>(hbuf, w2t, sb2, tb2,
                                                             xsb, tib, stk16, row0, SR);
  }

  k_gemm_qk<<<dim3(4, 32, 4), 256, 0, stream>>>(tib, mt, kwqb, qkb);
  k_score<<<4096, 256, 0, stream>>>(stk16, qkb, sbias, sg, sbt, tg, tbt,
                                    stacked, gated, weights);
}

// Round 18
// 408.728 us; speedup vs baseline: 1.3600x; 1.2237x over previous
//
#include <hip/hip_runtime.h>
#include <hip/hip_fp8.h>
#include <math.h>

typedef unsigned short u16;
typedef unsigned char u8;
typedef short short8 __attribute__((ext_vector_type(8)));
typedef float f32x4 __attribute__((ext_vector_type(4)));

#define TT 4
#define BB 4096
#define DIM 512
#define HDIM 1024
#define BD (BB*DIM)      // 2097152
#define D2 (DIM*DIM)     // 262144
#define NEXP 20

#define GLOAD16(gp, lp) __builtin_amdgcn_global_load_lds( \
    (__attribute__((address_space(1))) void*)(void*)(gp), \
    (__attribute__((address_space(3))) void*)(void*)(lp), 16, 0, 0)

__device__ __forceinline__ u16 f2b(float f) {
  union { float f; unsigned u; } x; x.f = f;
  unsigned r = x.u + 0x7FFFu + ((x.u >> 16) & 1u);
  return (u16)(r >> 16);
}
__device__ __forceinline__ float b2f(u16 v) {
  union { unsigned u; float f; } x; x.u = ((unsigned)v) << 16; return x.f;
}

// ---- fp8 e4m3 (OCP on gfx950) pack helpers ----
__device__ __forceinline__ unsigned pk4_fp8(float a, float b, float c, float d) {
#if __has_builtin(__builtin_amdgcn_cvt_pk_fp8_f32)
  int w = 0;
  w = __builtin_amdgcn_cvt_pk_fp8_f32(a, b, w, false);
  w = __builtin_amdgcn_cvt_pk_fp8_f32(c, d, w, true);
  return (unsigned)w;
#else
  __hip_fp8_e4m3 A(a), B(b), C(c), D(d);
  return (unsigned)A.__x | ((unsigned)B.__x << 8) |
         ((unsigned)C.__x << 16) | ((unsigned)D.__x << 24);
#endif
}
__device__ __forceinline__ u8 f2f8(float f) {
  __hip_fp8_e4m3 t(f);
  return (u8)t.__x;
}

__device__ __forceinline__ float wsum(float v) {
#pragma unroll
  for (int o = 32; o > 0; o >>= 1) v += __shfl_xor(v, o);
  return v;
}

// fast exact-enough GELU
__device__ __forceinline__ float fgelu(float v) {
  float u = 1.5957691216057308f * v * (1.0f + 0.044715f * v * v);
  return v / (1.0f + __expf(-u));
}

// ------ prep: mean, bf16 casts, fp8 casts (x unscaled), score-bias ----------
__global__ __launch_bounds__(256) void k_prep(const float* __restrict__ ti,
                                              const float* __restrict__ qwkb,
                                              const float* __restrict__ kbqb,
                                              u16* __restrict__ tib,
                                              u16* __restrict__ xsb,
                                              u8* __restrict__ tib8,
                                              u8* __restrict__ xsb8,
                                              float* __restrict__ sbias) {
  int gw = (blockIdx.x * 256 + threadIdx.x) >> 6;   // row b
  int lane = threadIdx.x & 63;
  int d0 = lane * 8;
  float x[4][8];
#pragma unroll
  for (int t = 0; t < 4; t++) {
    const float* p = ti + ((size_t)t * BB + gw) * DIM + d0;
    *(float4*)&x[t][0] = *(const float4*)p;
    *(float4*)&x[t][4] = *(const float4*)(p + 4);
  }
  float m[8];
#pragma unroll
  for (int j = 0; j < 8; j++)
    m[j] = (x[0][j] + x[1][j] + x[2][j] + x[3][j]) * 0.25f;
#pragma unroll
  for (int t = 0; t < 4; t++) {
    ushort4 c0 = { f2b(x[t][0]), f2b(x[t][1]), f2b(x[t][2]), f2b(x[t][3]) };
    ushort4 c1 = { f2b(x[t][4]), f2b(x[t][5]), f2b(x[t][6]), f2b(x[t][7]) };
    u16* q = tib + ((size_t)t * BB + gw) * DIM + d0;
    *(ushort4*)q = c0; *(ushort4*)(q + 4) = c1;
    uint2 p8 = { pk4_fp8(x[t][0], x[t][1], x[t][2], x[t][3]),
                 pk4_fp8(x[t][4], x[t][5], x[t][6], x[t][7]) };
    *(uint2*)(tib8 + ((size_t)t * BB + gw) * DIM + d0) = p8;
  }
  {
    ushort4 c0 = { f2b(m[0]), f2b(m[1]), f2b(m[2]), f2b(m[3]) };
    ushort4 c1 = { f2b(m[4]), f2b(m[5]), f2b(m[6]), f2b(m[7]) };
    u16* q = xsb + (size_t)gw * DIM + d0;
    *(ushort4*)q = c0; *(ushort4*)(q + 4) = c1;
    uint2 p8 = { pk4_fp8(m[0], m[1], m[2], m[3]),
                 pk4_fp8(m[4], m[5], m[6], m[7]) };
    *(uint2*)(xsb8 + (size_t)gw * DIM + d0) = p8;
  }
#pragma unroll
  for (int t = 0; t < 4; t++) {
    const float* wp = qwkb + (size_t)t * DIM + d0;
    float4 w0 = *(const float4*)wp, w1 = *(const float4*)(wp + 4);
    float s = x[t][0]*w0.x + x[t][1]*w0.y + x[t][2]*w0.z + x[t][3]*w0.w
            + x[t][4]*w1.x + x[t][5]*w1.y + x[t][6]*w1.z + x[t][7]*w1.w;
    s = wsum(s);
    if (lane == 0) sbias[(size_t)t * BB + gw] = s + kbqb[t];
  }
}

// ---- batched transpose+cast: (G,R,C) f32 -> (G,C,R) fp8 (x scale) ----------
__global__ __launch_bounds__(256) void k_tcast8(const float* __restrict__ in,
                                                u8* __restrict__ out,
                                                int R, int C, float scale) {
  __shared__ float tile[32][33];
  size_t gb = (size_t)blockIdx.z * R * C;
  in += gb; out += gb;
  int c0 = blockIdx.x * 32, r0 = blockIdx.y * 32;
  int tx = threadIdx.x & 31, ty = threadIdx.x >> 5;
#pragma unroll
  for (int j = 0; j < 4; j++)
    tile[ty + j * 8][tx] = in[(size_t)(r0 + ty + j * 8) * C + c0 + tx];
  __syncthreads();
#pragma unroll
  for (int j = 0; j < 4; j++)
    out[(size_t)(c0 + ty + j * 8) * R + r0 + tx] = f2f8(scale * tile[tx][ty + j * 8]);
}

// ---------------- plain cast f32 -> bf16 -------------------------------------
__global__ __launch_bounds__(256) void k_cast(const float* __restrict__ in,
                                              u16* __restrict__ out) {
  size_t i = ((size_t)blockIdx.x * 256 + threadIdx.x) * 4;
  float4 v = *(const float4*)(in + i);
  ushort4 b = { f2b(v.x), f2b(v.y), f2b(v.z), f2b(v.w) };
  *(ushort4*)(out + i) = b;
}

// --------------- small bias-vector precomputes -------------------------------
__global__ __launch_bounds__(256) void k_biasvec(const float* __restrict__ qw,
                                                 const float* __restrict__ kb,
                                                 const float* __restrict__ kw,
                                                 const float* __restrict__ qb,
                                                 float* __restrict__ qwkb,
                                                 float* __restrict__ kwqb,
                                                 float* __restrict__ kbqb) {
  int gw = (blockIdx.x * 256 + threadIdx.x) >> 6;
  int lane = threadIdx.x & 63;
  if (gw < 2048) {
    int t = gw >> 9, c = gw & 511;
    const float* row = qw + ((size_t)t * DIM + c) * DIM;
    const float* v = kb + (size_t)t * DIM;
    float s = 0;
#pragma unroll
    for (int j = 0; j < 8; j++) s += row[lane * 8 + j] * v[lane * 8 + j];
    s = wsum(s);
    if (lane == 0) qwkb[(size_t)t * DIM + c] = s;
  } else if (gw < 4096) {
    int t = (gw - 2048) >> 9, d = gw & 511;
    const float* row = kw + ((size_t)t * DIM + d) * DIM;
    const float* v = qb + (size_t)t * DIM;
    float s = 0;
#pragma unroll
    for (int j = 0; j < 8; j++) s += row[lane * 8 + j] * v[lane * 8 + j];
    s = wsum(s);
    if (lane == 0) kwqb[(size_t)t * DIM + d] = s;
  } else if (gw < 4100) {
    int t = gw - 4096;
    const float* a = kb + (size_t)t * DIM;
    const float* c = qb + (size_t)t * DIM;
    float s = 0;
#pragma unroll
    for (int j = 0; j < 8; j++) s += a[lane * 8 + j] * c[lane * 8 + j];
    s = wsum(s);
    if (lane == 0) kbqb[t] = s;
  }
}

// ---- 256x128 FP8 MFMA GEMM, 512 thr, BK=64 fp8 (byte-identical layout to ----
// bf16 BK=32), triple-ring counted vmcnt(3), swapped operands.
// LDS 72 KB -> 2 blocks/CU. Lane fragment = 8 fp8 = one `long`.
__device__ __forceinline__ void gemm8(const u8* __restrict__ Ag, int lda,
                                      const u8* __restrict__ Bg, int ldb,
                                      int K, f32x4 acc[4][4]) {
  __shared__ __align__(16) u8 lA[3][16384];   // 3 x (256 rows x 64 B)
  __shared__ __align__(16) u8 lB[3][8192];    // 3 x (128 rows x 64 B)
  const int tid = threadIdx.x;                // 0..511
  const int lane = tid & 63;
  const int wave = tid >> 6;
  const int wm = wave >> 1, wn = wave & 1;    // 4 x 2 wave grid, 64x64 tiles
  const int rl = lane & 15;
  const int q = lane >> 4;
  const int row = tid >> 2;                   // 0..127
  const int gc16 = (tid & 3) ^ ((row >> 1) & 3);        // pre-swizzled 16B chunk
  const u8* a0 = Ag + (size_t)row * lda + gc16 * 16;    // A rows 0..127
  const u8* a1 = a0 + (size_t)128 * lda;                // A rows 128..255
  const u8* b0 = Bg + (size_t)row * ldb + gc16 * 16;    // B rows 0..127
  const int swz = (rl >> 1) & 3;
  const int low8 = (q & 1) * 8;
  const int c16a = q >> 1;
  const int off0 = ((c16a + 0) ^ swz) * 16 + low8;      // ks=0 byte-in-row
  const int off1 = ((c16a + 2) ^ swz) * 16 + low8;      // ks=1
  const int arow0 = (wm * 64 + rl) * 64;
  const int brow0 = (wn * 64 + rl) * 64;
  const int nst = K >> 6;
  // prologue: stage tiles 0 and 1
  GLOAD16(a0, &lA[0][tid * 16]);
  GLOAD16(a1, &lA[0][8192 + tid * 16]);
  GLOAD16(b0, &lB[0][tid * 16]);
  GLOAD16(a0 + 64, &lA[1][tid * 16]);
  GLOAD16(a1 + 64, &lA[1][8192 + tid * 16]);
  GLOAD16(b0 + 64, &lB[1][tid * 16]);
  asm volatile("s_waitcnt vmcnt(3)" ::: "memory");      // tile0 landed
  __builtin_amdgcn_s_barrier();
  __builtin_amdgcn_sched_barrier(0);
  for (int k = 0; k < nst; ++k) {
    const int cur = k % 3;
    if (k + 2 < nst) {                   // issue tile k+2 into ring slot
      const int off = (k + 2) * 64;
      const int nb = (k + 2) % 3;
      GLOAD16(a0 + off, &lA[nb][tid * 16]);
      GLOAD16(a1 + off, &lA[nb][8192 + tid * 16]);
      GLOAD16(b0 + off, &lB[nb][tid * 16]);
    }
#pragma unroll
    for (int ks = 0; ks < 2; ks++) {
      const int co = ks ? off1 : off0;
      long bf[4];
#pragma unroll
      for (int nf = 0; nf < 4; nf++)
        bf[nf] = *(const long*)&lB[cur][brow0 + nf * 1024 + co];
      __builtin_amdgcn_s_setprio(1);
#pragma unroll
      for (int mf = 0; mf < 4; mf++) {
        long af = *(const long*)&lA[cur][arow0 + mf * 1024 + co];
#pragma unroll
        for (int nf = 0; nf < 4; nf++)
          acc[mf][nf] = __builtin_amdgcn_mfma_f32_16x16x32_fp8_fp8(bf[nf], af,
                                                                   acc[mf][nf], 0, 0, 0);
      }
      __builtin_amdgcn_s_setprio(0);
    }
    // counted wait: tile k+1 landed; tile k+2 (3 loads) stays in flight
    if (k + 2 < nst) asm volatile("s_waitcnt vmcnt(3)" ::: "memory");
    else             asm volatile("s_waitcnt vmcnt(0)" ::: "memory");
    __builtin_amdgcn_s_barrier();
    __builtin_amdgcn_sched_barrier(0);
  }
}

// ---------------- expert up-GEMM: h = gelu(x@W1 + b1), fp8 out (x8) ----------
// W1 stored x16 -> acc/16. Swapped epilogue: lane owns (row, 4 cols) -> u32.
__global__ __launch_bounds__(512, 4) void k_gemm_up(const u8* __restrict__ xsb8,
                                                 const u8* __restrict__ tib8,
                                                 const u8* __restrict__ w1t8,
                                                 const float* __restrict__ sb1,
                                                 const float* __restrict__ tb1,
                                                 u8* __restrict__ hbuf8,
                                                 int row0, int SR) {
  int ge = blockIdx.z;
  const u8* A;
  const float* bias;
  if (ge < 4) { A = xsb8; bias = sb1 + (size_t)ge * HDIM; }
  else {
    int te = ge - 4;
    A = tib8 + (size_t)(te >> 2) * BD;
    bias = tb1 + (size_t)te * HDIM;
  }
  A += (size_t)row0 * DIM;
  const u8* W = w1t8 + (size_t)ge * ((size_t)HDIM * DIM);
  int m0 = blockIdx.y * 256, n0 = blockIdx.x * 128;
  f32x4 acc[4][4] = {};
  gemm8(A + (size_t)m0 * DIM, DIM, W + (size_t)n0 * DIM, DIM, DIM, acc);
  u8* out = hbuf8 + (size_t)ge * ((size_t)SR * HDIM);
  const int lane = threadIdx.x & 63, wave = threadIdx.x >> 6;
  const int rl = lane & 15, c4 = (lane >> 4) * 4;
  const int wm = wave >> 1, wn = wave & 1;
#pragma unroll
  for (int mf = 0; mf < 4; mf++) {
    int row = m0 + wm * 64 + mf * 16 + rl;
#pragma unroll
    for (int nf = 0; nf < 4; nf++) {
      int col0 = n0 + wn * 64 + nf * 16 + c4;
      float4 bb = *(const float4*)(bias + col0);
      float h0 = fgelu(acc[mf][nf][0] * 0.0625f + bb.x);
      float h1 = fgelu(acc[mf][nf][1] * 0.0625f + bb.y);
      float h2 = fgelu(acc[mf][nf][2] * 0.0625f + bb.z);
      float h3 = fgelu(acc[mf][nf][3] * 0.0625f + bb.w);
      *(unsigned*)(out + (size_t)row * HDIM + col0) =
          pk4_fp8(8.f * h0, 8.f * h1, 8.f * h2, 8.f * h3);
    }
  }
}

// ---- down-GEMM: preLN bf16 = (h8@W2_8)/128 + b2 + residual -> stk16 ---------
__global__ __launch_bounds__(512, 4) void k_gemm_down(const u8* __restrict__ hbuf8,
                                                   const u8* __restrict__ w2t8,
                                                   const float* __restrict__ sb2,
                                                   const float* __restrict__ tb2,
                                                   const u16* __restrict__ xsb,
                                                   const u16* __restrict__ tib,
                                                   u16* __restrict__ stk16,
                                                   int row0, int SR) {
  int ge = blockIdx.z;
  int m0 = blockIdx.y * 256, n0 = blockIdx.x * 128;
  const u8* Ag = hbuf8 + (size_t)ge * ((size_t)SR * HDIM) + (size_t)m0 * HDIM;
  const u8* Bg = w2t8 + (size_t)ge * ((size_t)DIM * HDIM) + (size_t)n0 * HDIM;
  f32x4 acc[4][4] = {};
  gemm8(Ag, HDIM, Bg, HDIM, HDIM, acc);
  const float* bias; const u16* resb;
  int te = ge - 4;
  if (ge < 4) { bias = sb2 + (size_t)ge * DIM; resb = xsb; }
  else { bias = tb2 + (size_t)te * DIM; resb = tib + (size_t)(te >> 2) * BD; }
  const int lane = threadIdx.x & 63, wave = threadIdx.x >> 6;
  const int rl = lane & 15, c4 = (lane >> 4) * 4;
  const int wm = wave >> 1, wn = wave & 1;
  u16* outb = stk16 + (size_t)ge * BD;
  const float s = 1.0f / 128.0f;
#pragma unroll
  for (int mf = 0; mf < 4; mf++) {
    int grow = row0 + m0 + wm * 64 + mf * 16 + rl;
#pragma unroll
    for (int nf = 0; nf < 4; nf++) {
      int col0 = n0 + wn * 64 + nf * 16 + c4;
      float4 bb = *(const float4*)(bias + col0);
      ushort4 rr = *(const ushort4*)(resb + (size_t)grow * DIM + col0);
      ushort4 y;
      y.x = f2b(acc[mf][nf][0] * s + bb.x + b2f(rr.x));
      y.y = f2b(acc[mf][nf][1] * s + bb.y + b2f(rr.y));
      y.z = f2b(acc[mf][nf][2] * s + bb.z + b2f(rr.z));
      y.w = f2b(acc[mf][nf][3] * s + bb.w + b2f(rr.w));
      *(ushort4*)(outb + (size_t)grow * DIM + col0) = y;
    }
  }
}

// ---- 128x128 bf16 MFMA GEMM, BK=32, triple-ring (small GEMMs: mt, qk) -------
template <bool SWAPPED>
__device__ __forceinline__ void gemm128r(const u16* __restrict__ Ag, int lda,
                                         const u16* __restrict__ Bg, int ldb,
                                         int K, f32x4 acc[4][4]) {
  __shared__ __align__(16) u16 lA[3][4096];
  __shared__ __align__(16) u16 lB[3][4096];
  const int tid = threadIdx.x;
  const int lane = tid & 63;
  const int wave = tid >> 6;
  const int wm = wave >> 1, wn = wave & 1;
  const int rl = lane & 15;
  const int gc = ((tid & 3) ^ ((tid >> 3) & 3)) * 8;
  const int hs = ((lane >> 4) ^ ((rl >> 1) & 3)) * 8;
  const u16* a0 = Ag + (size_t)(tid >> 2) * lda + gc;
  const u16* a1 = a0 + (size_t)64 * lda;
  const u16* b0 = Bg + (size_t)(tid >> 2) * ldb + gc;
  const u16* b1 = b0 + (size_t)64 * ldb;
  const int ao = (wm * 64 + rl) * 32 + hs;
  const int bo = (wn * 64 + rl) * 32 + hs;
  const int nst = K >> 5;
  GLOAD16(a0, &lA[0][tid * 8]);
  GLOAD16(a1, &lA[0][2048 + tid * 8]);
  GLOAD16(b0, &lB[0][tid * 8]);
  GLOAD16(b1, &lB[0][2048 + tid * 8]);
  GLOAD16(a0 + 32, &lA[1][tid * 8]);
  GLOAD16(a1 + 32, &lA[1][2048 + tid * 8]);
  GLOAD16(b0 + 32, &lB[1][tid * 8]);
  GLOAD16(b1 + 32, &lB[1][2048 + tid * 8]);
  asm volatile("s_waitcnt vmcnt(4)" ::: "memory");
  __builtin_amdgcn_s_barrier();
  __builtin_amdgcn_sched_barrier(0);
  for (int k = 0; k < nst; ++k) {
    const int cur = k % 3;
    if (k + 2 < nst) {
      const int off = (k + 2) * 32;
      const int nb = (k + 2) % 3;
      GLOAD16(a0 + off, &lA[nb][tid * 8]);
      GLOAD16(a1 + off, &lA[nb][2048 + tid * 8]);
      GLOAD16(b0 + off, &lB[nb][tid * 8]);
      GLOAD16(b1 + off, &lB[nb][2048 + tid * 8]);
    }
    short8 af[4], bf[4];
#pragma unroll
    for (int i = 0; i < 4; i++) {
      af[i] = *(const short8*)&lA[cur][ao + i * 512];
      bf[i] = *(const short8*)&lB[cur][bo + i * 512];
    }
    __builtin_amdgcn_s_setprio(1);
    if (SWAPPED) {
#pragma unroll
      for (int mi = 0; mi < 4; mi++)
#pragma unroll
        for (int ni = 0; ni < 4; ni++)
          acc[mi][ni] = __builtin_amdgcn_mfma_f32_16x16x32_bf16(bf[ni], af[mi],
                                                                acc[mi][ni], 0, 0, 0);
    } else {
#pragma unroll
      for (int mi = 0; mi < 4; mi++)
#pragma unroll
        for (int ni = 0; ni < 4; ni++)
          acc[mi][ni] = __builtin_amdgcn_mfma_f32_16x16x32_bf16(af[mi], bf[ni],
                                                                acc[mi][ni], 0, 0, 0);
    }
    __builtin_amdgcn_s_setprio(0);
    if (k + 2 < nst) asm volatile("s_waitcnt vmcnt(4)" ::: "memory");
    else             asm volatile("s_waitcnt vmcnt(0)" ::: "memory");
    __builtin_amdgcn_s_barrier();
    __builtin_amdgcn_sched_barrier(0);
  }
}

// ---------------- MT[t] = kw[t] @ qw[t]^T  (bf16 out) ------------------------
__global__ __launch_bounds__(256) void k_gemm_mt(const u16* __restrict__ kwb,
                                                 const u16* __restrict__ qwb,
                                                 u16* __restrict__ mt) {
  int t = blockIdx.z;
  int m0 = blockIdx.y * 128, n0 = blockIdx.x * 128;
  f32x4 acc[4][4] = {};
  gemm128r<true>(kwb + (size_t)t * D2 + (size_t)m0 * DIM, DIM,
                 qwb + (size_t)t * D2 + (size_t)n0 * DIM, DIM, DIM, acc);
  const int lane = threadIdx.x & 63, wave = threadIdx.x >> 6;
  const int rl = lane & 15, c4 = (lane >> 4) * 4;
  const int wm = wave >> 1, wn = wave & 1;
#pragma unroll
  for (int mf = 0; mf < 4; mf++) {
    int row = m0 + wm * 64 + mf * 16 + rl;
#pragma unroll
    for (int nf = 0; nf < 4; nf++) {
      int col0 = n0 + wn * 64 + nf * 16 + c4;
      ushort4 y = { f2b(acc[mf][nf][0]), f2b(acc[mf][nf][1]),
                    f2b(acc[mf][nf][2]), f2b(acc[mf][nf][3]) };
      *(ushort4*)(mt + (size_t)t * D2 + (size_t)row * DIM + col0) = y;
    }
  }
}

// ------------- qkb[t] = bf16(x[t] @ MT[t]^T + kwqb[t]) -----------------------
__global__ __launch_bounds__(256) void k_gemm_qk(const u16* __restrict__ tib,
                                                 const u16* __restrict__ mt,
                                                 const float* __restrict__ kwqb,
                                                 u16* __restrict__ qkb) {
  int t = blockIdx.z;
  int m0 = blockIdx.y * 128, n0 = blockIdx.x * 128;
  f32x4 acc[4][4] = {};
  gemm128r<true>(tib + (size_t)t * BD + (size_t)m0 * DIM, DIM,
                 mt + (size_t)t * D2 + (size_t)n0 * DIM, DIM, DIM, acc);
  const int lane = threadIdx.x & 63, wave = threadIdx.x >> 6;
  const int rl = lane & 15, c4 = (lane >> 4) * 4;
  const int wm = wave >> 1, wn = wave & 1;
#pragma unroll
  for (int mf = 0; mf < 4; mf++) {
    int row = m0 + wm * 64 + mf * 16 + rl;
#pragma unroll
    for (int nf = 0; nf < 4; nf++) {
      int col0 = n0 + wn * 64 + nf * 16 + c4;
      float4 bb = *(const float4*)(kwqb + (size_t)t * DIM + col0);
      ushort4 y;
      y.x = f2b(acc[mf][nf][0] + bb.x);
      y.y = f2b(acc[mf][nf][1] + bb.y);
      y.z = f2b(acc[mf][nf][2] + bb.z);
      y.w = f2b(acc[mf][nf][3] + bb.w);
      *(ushort4*)(qkb + (size_t)t * BD + (size_t)row * DIM + col0) = y;
    }
  }
}

// ---- fused LN + scores + softmax + gating (one wave per (t,b)) --------------
__global__ __launch_bounds__(256) void k_score(const u16* __restrict__ stk16,
                                               const u16* __restrict__ qkb,
                                               const float* __restrict__ sbias,
                                               const float* __restrict__ sg,
                                               const float* __restrict__ sbt,
                                               const float* __restrict__ tg,
                                               const float* __restrict__ tbt,
                                               float* __restrict__ stacked,
                                               float* __restrict__ gated,
                                               float* __restrict__ wout) {
  int gw = (blockIdx.x * 256 + threadIdx.x) >> 6;
  int lane = threadIdx.x & 63;
  int b = gw & (BB - 1), t = gw >> 12;
  int d0 = lane * 8;
  size_t rowoff = ((size_t)t * BB + b) * DIM + d0;
  float qr[8];
  {
    ushort4 q0 = *(const ushort4*)(qkb + rowoff);
    ushort4 q1 = *(const ushort4*)(qkb + rowoff + 4);
    qr[0] = b2f(q0.x); qr[1] = b2f(q0.y); qr[2] = b2f(q0.z); qr[3] = b2f(q0.w);
    qr[4] = b2f(q1.x); qr[5] = b2f(q1.y); qr[6] = b2f(q1.z); qr[7] = b2f(q1.w);
  }
  float stv[8][8];
  float dots[8];
#pragma unroll
  for (int n = 0; n < 8; n++) {
    int e = (n < 4) ? n : (4 + t * 4 + (n - 4));
    const u16* sp = stk16 + ((size_t)e * BB + b) * DIM + d0;
    ushort4 v0 = *(const ushort4*)sp;
    ushort4 v1 = *(const ushort4*)(sp + 4);
    float v[8] = { b2f(v0.x), b2f(v0.y), b2f(v0.z), b2f(v0.w),
                   b2f(v1.x), b2f(v1.y), b2f(v1.z), b2f(v1.w) };
    float S = 0, Q = 0;
#pragma unroll
    for (int j = 0; j < 8; j++) { S += v[j]; Q += v[j] * v[j]; }
    S = wsum(S); Q = wsum(Q);
    float mu = S * (1.0f / DIM);
    float var = Q * (1.0f / DIM) - mu * mu;
    float rs = rsqrtf(var + 1e-5f);
    const float* gp; const float* bp;
    if (n < 4) { gp = sg + (size_t)n * DIM; bp = sbt + (size_t)n * DIM; }
    else {
      int te = t * 4 + (n - 4);
      gp = tg + (size_t)te * DIM; bp = tbt + (size_t)te * DIM;
    }
    float4 g0 = *(const float4*)(gp + d0), g1 = *(const float4*)(gp + d0 + 4);
    float4 b0 = *(const float4*)(bp + d0), b1 = *(const float4*)(bp + d0 + 4);
    float gv[8] = { g0.x, g0.y, g0.z, g0.w, g1.x, g1.y, g1.z, g1.w };
    float bv[8] = { b0.x, b0.y, b0.z, b0.w, b1.x, b1.y, b1.z, b1.w };
    float dd = 0;
#pragma unroll
    for (int j = 0; j < 8; j++) {
      float y = (v[j] - mu) * rs * gv[j] + bv[j];
      stv[n][j] = y;
      dd += y * qr[j];
    }
    float* so = stacked + (((size_t)t * 8 + n) * BB + b) * DIM + d0;
    *(float4*)so = *(float4*)&stv[n][0];
    *(float4*)(so + 4) = *(float4*)&stv[n][4];
    dots[n] = wsum(dd);
  }
  float sb = sbias[(size_t)t * BB + b];
  const float inv = 0.04419417382415922f;  // 1/sqrt(512)
  float sc[8], e[8];
  float mx = -1e30f;
#pragma unroll
  for (int n = 0; n < 8; n++) { sc[n] = (dots[n] + sb) * inv; mx = fmaxf(mx, sc[n]); }
  float den = 0;
#pragma unroll
  for (int n = 0; n < 8; n++) { e[n] = expf(sc[n] - mx); den += e[n]; }
  float rden = 1.0f / den;
  float wv[8];
#pragma unroll
  for (int n = 0; n < 8; n++) wv[n] = e[n] * rden;
  float wsel = 0;
#pragma unroll
  for (int n = 0; n < 8; n++) wsel = (lane == n) ? wv[n] : wsel;
  if (lane < 8) wout[((size_t)t * BB + b) * 8 + lane] = wsel;
  float g[8];
#pragma unroll
  for (int j = 0; j < 8; j++) {
    float s = 0;
#pragma unroll
    for (int n = 0; n < 8; n++) s += wv[n] * stv[n][j];
    g[j] = s;
  }
  float* go = gated + rowoff;
  *(float4*)(go) = *(float4*)&g[0];
  *(float4*)(go + 4) = *(float4*)&g[4];
}

// ============================ host launcher ==================================
extern "C" void kernel_launch(void* const* d_in, const int* in_sizes, int n_in,
                              void* d_out, int out_size, void* d_ws, size_t ws_size,
                              hipStream_t stream) {
  const float* ti  = (const float*)d_in[0];
  const float* sw1 = (const float*)d_in[1];
  const float* sb1 = (const float*)d_in[2];
  const float* sw2 = (const float*)d_in[3];
  const float* sb2 = (const float*)d_in[4];
  const float* sg  = (const float*)d_in[5];
  const float* sbt = (const float*)d_in[6];
  const float* tw1 = (const float*)d_in[7];
  const float* tb1 = (const float*)d_in[8];
  const float* tw2 = (const float*)d_in[9];
  const float* tb2 = (const float*)d_in[10];
  const float* tg  = (const float*)d_in[11];
  const float* tbt = (const float*)d_in[12];
  const float* qw  = (const float*)d_in[13];
  const float* qb  = (const float*)d_in[14];
  const float* kw  = (const float*)d_in[15];
  const float* kb  = (const float*)d_in[16];

  float* out = (float*)d_out;
  float* gated   = out;                                   // T*B*D
  float* weights = out + (size_t)TT * BB * DIM;           // T*B*8
  float* stacked = weights + (size_t)TT * BB * 8;         // T*8*B*D

  char* ws = (char*)d_ws;
  u16*   tib   = (u16*)(ws);                    // 16,777,216
  u16*   xsb   = (u16*)(ws + 16777216);         //  4,194,304
  u8*    w1t8  = (u8*)(ws + 20971520);          // 10,485,760 (fp8, x16)
  u8*    w2t8  = (u8*)(ws + 31457280);          // 10,485,760 (fp8, x16)
  u16*   qwb   = (u16*)(ws + 41943040);         //  2,097,152
  u16*   kwb   = (u16*)(ws + 44040192);         //  2,097,152
  u16*   mt    = (u16*)(ws + 46137344);         //  2,097,152
  float* sbias = (float*)(ws + 48234496);       //     65,536
  float* qwkb  = (float*)(ws + 48300032);       //      8,192
  float* kwqb  = (float*)(ws + 48308224);       //      8,192
  float* kbqb  = (float*)(ws + 48316416);       //      1,024
  u8*    tib8  = (u8*)(ws + 48317440);          //  8,388,608 (fp8 x, x1)
  u8*    xsb8  = (u8*)(ws + 56706048);          //  2,097,152
  u16*   qkb   = (u16*)(ws + 58803200);         // 16,777,216
  u16*   stk16 = (u16*)(ws + 75580416);         // 83,886,080
  u8*    hbuf8 = (u8*)(ws + 159466496);         // SR*HDIM*20 (fp8 h, x8)

  const size_t hoff = 159466496;
  int SR = 512;
  if (ws_size >= hoff + (size_t)NEXP * BB * HDIM) SR = BB;            // 243 MB
  else if (ws_size >= hoff + (size_t)NEXP * 1024 * HDIM) SR = 1024;

  // weight / gate preprocessing (W1,W2 -> fp8 x16; qw,kw -> bf16)
  k_tcast8<<<dim3(32, 16, 4), 256, 0, stream>>>(sw1, w1t8, DIM, HDIM, 16.f);
  k_tcast8<<<dim3(32, 16, 16), 256, 0, stream>>>(tw1, w1t8 + (size_t)4 * HDIM * DIM, DIM, HDIM, 16.f);
  k_tcast8<<<dim3(16, 32, 4), 256, 0, stream>>>(sw2, w2t8, HDIM, DIM, 16.f);
  k_tcast8<<<dim3(16, 32, 16), 256, 0, stream>>>(tw2, w2t8 + (size_t)4 * DIM * HDIM, HDIM, DIM, 16.f);
  k_cast<<<1024, 256, 0, stream>>>(qw, qwb);
  k_cast<<<1024, 256, 0, stream>>>(kw, kwb);
  k_biasvec<<<1025, 256, 0, stream>>>(qw, kb, kw, qb, qwkb, kwqb, kbqb);
  k_prep<<<1024, 256, 0, stream>>>(ti, qwkb, kbqb, tib, xsb, tib8, xsb8, sbias);
  k_gemm_mt<<<dim3(4, 4, 4), 256, 0, stream>>>(kwb, qwb, mt);

  // expert FFNs: fp8 operands, 256x128 tiles, BK=64-fp8 triple-ring pipeline
  for (int row0 = 0; row0 < BB; row0 += SR) {
    k_gemm_up<<<dim3(8, SR / 256, NEXP), 512, 0, stream>>>(xsb8, tib8, w1t8, sb1, tb1,
                                                           hbuf8, row0, SR);
    k_gemm_down<<<dim3(4, SR / 256, NEXP), 512, 0, stream>>>(hbuf8, w2t8, sb2, tb2,
                                                             xsb, tib, stk16, row0, SR);
  }

  k_gemm_qk<<<dim3(4, 32, 4), 256, 0, stream>>>(tib, mt, kwqb, qkb);
  k_score<<<4096, 256, 0, stream>>>(stk16, qkb, sbias, sg, sbt, tg, tbt,
                                    stacked, gated, weights);
}